// Round 1
// baseline (2998.436 us; speedup 1.0000x reference)
//
#include <hip/hip_runtime.h>

#define NN  50000
#define NE  600000
#define CC  128
#define NFF 256
#define ECH 64
#define EIN 192   // ECH + CC

__device__ __forceinline__ float sspf(float v) {
    // softplus(v) - log(2), numerically stable
    float sp = (v > 0.0f) ? (v + log1pf(__expf(-v))) : log1pf(__expf(v));
    return sp - 0.693147180559945f;
}

// ---- K0: zero the agg buffer (avoid relying on memset capture semantics) ----
__global__ void k0_zero(float* __restrict__ p, long n4) {
    long i = (long)blockIdx.x * blockDim.x + threadIdx.x;
    long stride = (long)gridDim.x * blockDim.x;
    float4 z = {0.f, 0.f, 0.f, 0.f};
    for (; i < n4; i += stride) ((float4*)p)[i] = z;
}

// ---- K1: h[N,NF] = x[N,C] @ W_lin1[C,NF] ----
// block: 256 threads = 4 node-groups x 64 channel-groups; thread tile 4x4
__global__ __launch_bounds__(256) void k1_h(const float* __restrict__ x,
                                            const float* __restrict__ W,
                                            float* __restrict__ h) {
    __shared__ __align__(16) float xs[16][CC];
    int n0 = blockIdx.x * 16;
    int tid = threadIdx.x;
    for (int i = tid; i < 16 * CC / 4; i += 256) {
        int nd = i >> 5;            // CC/4 = 32 float4 per row
        int c4 = i & 31;
        *(float4*)&xs[nd][c4 * 4] = ((const float4*)x)[(size_t)(n0 + nd) * 32 + c4];
    }
    __syncthreads();
    int j0 = (tid & 63) * 4;
    int i0 = (tid >> 6) * 4;
    float acc[4][4] = {};
    #pragma unroll 4
    for (int k = 0; k < CC; ++k) {
        float4 b = *(const float4*)&W[k * NFF + j0];
        #pragma unroll
        for (int i = 0; i < 4; ++i) {
            float a = xs[i0 + i][k];
            acc[i][0] = fmaf(a, b.x, acc[i][0]);
            acc[i][1] = fmaf(a, b.y, acc[i][1]);
            acc[i][2] = fmaf(a, b.z, acc[i][2]);
            acc[i][3] = fmaf(a, b.w, acc[i][3]);
        }
    }
    #pragma unroll
    for (int i = 0; i < 4; ++i) {
        float4 v = {acc[i][0], acc[i][1], acc[i][2], acc[i][3]};
        *(float4*)&h[(size_t)(n0 + i0 + i) * NFF + j0] = v;
    }
}

// ---- K2: fused filter-net + gather(h[col]) + modulate + scatter-add(agg[row]) ----
// per block: TILE=16 edges. Wf = ssp(ea@Wf1+b1)@Wf2+b2 ; agg[row] += h[col]*Wf
__global__ __launch_bounds__(256) void k2_filter_scatter(
        const float* __restrict__ ea, const int* __restrict__ eidx,
        const float* __restrict__ Wf1, const float* __restrict__ bf1,
        const float* __restrict__ Wf2, const float* __restrict__ bf2,
        const float* __restrict__ h, float* __restrict__ agg) {
    __shared__ __align__(16) float eas[16][ECH];
    __shared__ __align__(16) float t1s[16][NFF];
    int e0 = blockIdx.x * 16;
    int tid = threadIdx.x;
    {   // 16 edges x 64 ch = 256 float4: one per thread
        int e = tid >> 4;           // ECH/4 = 16 float4 per row
        int c4 = tid & 15;
        *(float4*)&eas[e][c4 * 4] = ((const float4*)ea)[(size_t)(e0 + e) * 16 + c4];
    }
    __syncthreads();
    int j0 = (tid & 63) * 4;
    int i0 = (tid >> 6) * 4;

    // phase 1: t1 = ssp(ea @ Wf1 + b1)   [16 x 256], K=64
    float acc[4][4] = {};
    #pragma unroll 4
    for (int k = 0; k < ECH; ++k) {
        float4 b = *(const float4*)&Wf1[k * NFF + j0];
        #pragma unroll
        for (int i = 0; i < 4; ++i) {
            float a = eas[i0 + i][k];
            acc[i][0] = fmaf(a, b.x, acc[i][0]);
            acc[i][1] = fmaf(a, b.y, acc[i][1]);
            acc[i][2] = fmaf(a, b.z, acc[i][2]);
            acc[i][3] = fmaf(a, b.w, acc[i][3]);
        }
    }
    float4 b1 = *(const float4*)&bf1[j0];
    #pragma unroll
    for (int i = 0; i < 4; ++i) {
        float4 v;
        v.x = sspf(acc[i][0] + b1.x);
        v.y = sspf(acc[i][1] + b1.y);
        v.z = sspf(acc[i][2] + b1.z);
        v.w = sspf(acc[i][3] + b1.w);
        *(float4*)&t1s[i0 + i][j0] = v;
    }
    __syncthreads();

    // phase 2: Wf = t1 @ Wf2 + b2   [16 x 256], K=256
    float acc2[4][4] = {};
    #pragma unroll 4
    for (int k = 0; k < NFF; ++k) {
        float4 b = *(const float4*)&Wf2[k * NFF + j0];
        #pragma unroll
        for (int i = 0; i < 4; ++i) {
            float a = t1s[i0 + i][k];
            acc2[i][0] = fmaf(a, b.x, acc2[i][0]);
            acc2[i][1] = fmaf(a, b.y, acc2[i][1]);
            acc2[i][2] = fmaf(a, b.z, acc2[i][2]);
            acc2[i][3] = fmaf(a, b.w, acc2[i][3]);
        }
    }
    float4 b2 = *(const float4*)&bf2[j0];

    // gather h[col], modulate, scatter into agg[row]
    #pragma unroll
    for (int i = 0; i < 4; ++i) {
        int e = e0 + i0 + i;
        int r = eidx[e];
        int c = eidx[NE + e];
        float4 hv = *(const float4*)&h[(size_t)c * NFF + j0];
        float* ap = &agg[(size_t)r * NFF + j0];
        atomicAdd(ap + 0, hv.x * (acc2[i][0] + b2.x));
        atomicAdd(ap + 1, hv.y * (acc2[i][1] + b2.y));
        atomicAdd(ap + 2, hv.z * (acc2[i][2] + b2.z));
        atomicAdd(ap + 3, hv.w * (acc2[i][3] + b2.w));
    }
}

// ---- K3: x_out = relu(ssp(agg@Wl2+b2)@Wl3+b3) + x ----
// block: 128 threads = 4 node-groups x 32 channel-groups; 16 nodes/block
__global__ __launch_bounds__(128) void k3_node(
        const float* __restrict__ agg,
        const float* __restrict__ Wl2, const float* __restrict__ bl2,
        const float* __restrict__ Wl3, const float* __restrict__ bl3,
        const float* __restrict__ x, float* __restrict__ xo) {
    __shared__ __align__(16) float as[16][NFF];
    __shared__ __align__(16) float t2[16][CC];
    int n0 = blockIdx.x * 16;
    int tid = threadIdx.x;
    for (int i = tid; i < 16 * NFF / 4; i += 128) {
        int nd = i >> 6;            // NFF/4 = 64 float4 per row
        int c4 = i & 63;
        *(float4*)&as[nd][c4 * 4] = ((const float4*)agg)[(size_t)(n0 + nd) * 64 + c4];
    }
    __syncthreads();
    int j0 = (tid & 31) * 4;
    int i0 = (tid >> 5) * 4;

    float acc[4][4] = {};
    #pragma unroll 4
    for (int k = 0; k < NFF; ++k) {
        float4 b = *(const float4*)&Wl2[k * CC + j0];
        #pragma unroll
        for (int i = 0; i < 4; ++i) {
            float a = as[i0 + i][k];
            acc[i][0] = fmaf(a, b.x, acc[i][0]);
            acc[i][1] = fmaf(a, b.y, acc[i][1]);
            acc[i][2] = fmaf(a, b.z, acc[i][2]);
            acc[i][3] = fmaf(a, b.w, acc[i][3]);
        }
    }
    float4 b2v = *(const float4*)&bl2[j0];
    #pragma unroll
    for (int i = 0; i < 4; ++i) {
        float4 v;
        v.x = sspf(acc[i][0] + b2v.x);
        v.y = sspf(acc[i][1] + b2v.y);
        v.z = sspf(acc[i][2] + b2v.z);
        v.w = sspf(acc[i][3] + b2v.w);
        *(float4*)&t2[i0 + i][j0] = v;
    }
    __syncthreads();

    float acc3[4][4] = {};
    #pragma unroll 4
    for (int k = 0; k < CC; ++k) {
        float4 b = *(const float4*)&Wl3[k * CC + j0];
        #pragma unroll
        for (int i = 0; i < 4; ++i) {
            float a = t2[i0 + i][k];
            acc3[i][0] = fmaf(a, b.x, acc3[i][0]);
            acc3[i][1] = fmaf(a, b.y, acc3[i][1]);
            acc3[i][2] = fmaf(a, b.z, acc3[i][2]);
            acc3[i][3] = fmaf(a, b.w, acc3[i][3]);
        }
    }
    float4 b3v = *(const float4*)&bl3[j0];
    #pragma unroll
    for (int i = 0; i < 4; ++i) {
        size_t base = (size_t)(n0 + i0 + i) * CC + j0;
        float4 xv = *(const float4*)&x[base];
        float4 v;
        v.x = fmaxf(acc3[i][0] + b3v.x, 0.f) + xv.x;
        v.y = fmaxf(acc3[i][1] + b3v.y, 0.f) + xv.y;
        v.z = fmaxf(acc3[i][2] + b3v.z, 0.f) + xv.z;
        v.w = fmaxf(acc3[i][3] + b3v.w, 0.f) + xv.w;
        *(float4*)&xo[base] = v;
    }
}

// ---- K4: e_out = tanh([edge_attr, xo[row]+xo[col]] @ W_e + b_e) ----
__global__ __launch_bounds__(128) void k4_edge_mlp(
        const float* __restrict__ ea, const int* __restrict__ eidx,
        const float* __restrict__ xo, const float* __restrict__ We,
        const float* __restrict__ be, float* __restrict__ eo) {
    __shared__ __align__(16) float s[16][EIN];
    int e0 = blockIdx.x * 16;
    int tid = threadIdx.x;
    for (int i = tid; i < 16 * ECH / 4; i += 128) {
        int e = i >> 4;
        int c4 = i & 15;
        *(float4*)&s[e][c4 * 4] = ((const float4*)ea)[(size_t)(e0 + e) * 16 + c4];
    }
    #pragma unroll
    for (int e = 0; e < 16; ++e) {
        int r = eidx[e0 + e];
        int c = eidx[NE + e0 + e];
        s[e][ECH + tid] = xo[(size_t)r * CC + tid] + xo[(size_t)c * CC + tid];
    }
    __syncthreads();
    int j0 = (tid & 31) * 4;
    int i0 = (tid >> 5) * 4;
    float acc[4][4] = {};
    #pragma unroll 4
    for (int k = 0; k < EIN; ++k) {
        float4 b = *(const float4*)&We[k * CC + j0];
        #pragma unroll
        for (int i = 0; i < 4; ++i) {
            float a = s[i0 + i][k];
            acc[i][0] = fmaf(a, b.x, acc[i][0]);
            acc[i][1] = fmaf(a, b.y, acc[i][1]);
            acc[i][2] = fmaf(a, b.z, acc[i][2]);
            acc[i][3] = fmaf(a, b.w, acc[i][3]);
        }
    }
    float4 bb = *(const float4*)&be[j0];
    #pragma unroll
    for (int i = 0; i < 4; ++i) {
        size_t base = (size_t)(e0 + i0 + i) * CC + j0;
        float4 v;
        v.x = tanhf(acc[i][0] + bb.x);
        v.y = tanhf(acc[i][1] + bb.y);
        v.z = tanhf(acc[i][2] + bb.z);
        v.w = tanhf(acc[i][3] + bb.w);
        *(float4*)&eo[base] = v;
    }
}

extern "C" void kernel_launch(void* const* d_in, const int* in_sizes, int n_in,
                              void* d_out, int out_size, void* d_ws, size_t ws_size,
                              hipStream_t stream) {
    const float* x   = (const float*)d_in[0];
    const int*   ei  = (const int*)d_in[1];
    const float* ea  = (const float*)d_in[2];
    // d_in[3] = x_pos (unused by reference)
    const float* Wf1 = (const float*)d_in[4];
    const float* bf1 = (const float*)d_in[5];
    const float* Wf2 = (const float*)d_in[6];
    const float* bf2 = (const float*)d_in[7];
    const float* Wl1 = (const float*)d_in[8];
    const float* Wl2 = (const float*)d_in[9];
    const float* bl2 = (const float*)d_in[10];
    const float* Wl3 = (const float*)d_in[11];
    const float* bl3 = (const float*)d_in[12];
    const float* We  = (const float*)d_in[13];
    const float* be  = (const float*)d_in[14];

    float* xo = (float*)d_out;                 // [N, C]
    float* eo = xo + (size_t)NN * CC;          // [E, C]

    // workspace: agg [N,NF] always in ws; h [N,NF] in ws if it fits,
    // otherwise staged in the e_out region (overwritten later by K4).
    float* agg = (float*)d_ws;
    size_t one = (size_t)NN * NFF;
    float* h = (ws_size >= 2 * one * sizeof(float)) ? (agg + one) : eo;

    k0_zero<<<1024, 256, 0, stream>>>(agg, (long)(one / 4));
    k1_h<<<NN / 16, 256, 0, stream>>>(x, Wl1, h);
    k2_filter_scatter<<<NE / 16, 256, 0, stream>>>(ea, ei, Wf1, bf1, Wf2, bf2, h, agg);
    k3_node<<<NN / 16, 128, 0, stream>>>(agg, Wl2, bl2, Wl3, bl3, x, xo);
    k4_edge_mlp<<<NE / 16, 128, 0, stream>>>(ea, ei, xo, We, be, eo);
}

// Round 2
// 1765.769 us; speedup vs baseline: 1.6981x; 1.6981x over previous
//
#include <hip/hip_runtime.h>

#define NN  50000
#define NE  600000
#define CC  128
#define NFF 256
#define ECH 64
#define EIN 192   // ECH + CC

typedef __attribute__((ext_vector_type(8))) short bf16x8;
typedef __attribute__((ext_vector_type(4))) short bf16x4;
typedef __attribute__((ext_vector_type(4))) float f32x4;

__device__ __forceinline__ float sspf(float v) {
    float sp = (v > 0.0f) ? (v + log1pf(__expf(-v))) : log1pf(__expf(v));
    return sp - 0.693147180559945f;
}
// fp32 -> bf16 round-to-nearest-even (inputs are well-behaved, no NaN path)
__device__ __forceinline__ short bf16r(float f) {
    unsigned u = __float_as_uint(f);
    u = (u + 0x7FFFu + ((u >> 16) & 1u)) >> 16;
    return (short)u;
}

// ---- pack weights to bf16 fragment-linear layout for mfma_16x16x32 B-operand
// packed[((ks*(N/16)+n16)*64 + lane)*8 + j] = B[ks*32 + (lane>>4)*8 + j][n16*16 + (lane&15)]
__global__ void kpack(const float* __restrict__ Wf1, const float* __restrict__ Wf2,
                      const float* __restrict__ We, short* __restrict__ p) {
    int i = blockIdx.x * 256 + threadIdx.x;
    if (i < 16384) {                       // Wf1 [64][256]: ks 0..1, n16 0..15
        int j = i & 7, lane = (i >> 3) & 63, n16 = (i >> 9) & 15, ks = i >> 13;
        int k = ks * 32 + (lane >> 4) * 8 + j, col = n16 * 16 + (lane & 15);
        p[i] = bf16r(Wf1[k * NFF + col]);
    } else if (i < 16384 + 65536) {        // Wf2 [256][256]: ks 0..7
        int t = i - 16384;
        int j = t & 7, lane = (t >> 3) & 63, n16 = (t >> 9) & 15, ks = t >> 13;
        int k = ks * 32 + (lane >> 4) * 8 + j, col = n16 * 16 + (lane & 15);
        p[i] = bf16r(Wf2[k * NFF + col]);
    } else if (i < 16384 + 65536 + 24576) { // We [192][128]: ks 0..5, n16 0..7
        int t = i - 81920;
        int j = t & 7, lane = (t >> 3) & 63, n16 = (t >> 9) & 7, ks = t >> 12;
        int k = ks * 32 + (lane >> 4) * 8 + j, col = n16 * 16 + (lane & 15);
        p[i] = bf16r(We[k * CC + col]);
    }
}

// ---- K0: zero agg ----
__global__ void k0_zero(float* __restrict__ p, long n4) {
    long i = (long)blockIdx.x * blockDim.x + threadIdx.x;
    long stride = (long)gridDim.x * blockDim.x;
    float4 z = {0.f, 0.f, 0.f, 0.f};
    for (; i < n4; i += stride) ((float4*)p)[i] = z;
}

// ---- K1: h[N,NF] = x[N,C] @ W_lin1[C,NF]  (fp32 VALU, small) ----
__global__ __launch_bounds__(256) void k1_h(const float* __restrict__ x,
                                            const float* __restrict__ W,
                                            float* __restrict__ h) {
    __shared__ __align__(16) float xs[16][CC];
    int n0 = blockIdx.x * 16;
    int tid = threadIdx.x;
    for (int i = tid; i < 16 * CC / 4; i += 256) {
        int nd = i >> 5;
        int c4 = i & 31;
        *(float4*)&xs[nd][c4 * 4] = ((const float4*)x)[(size_t)(n0 + nd) * 32 + c4];
    }
    __syncthreads();
    int j0 = (tid & 63) * 4;
    int i0 = (tid >> 6) * 4;
    float acc[4][4] = {};
    #pragma unroll 4
    for (int k = 0; k < CC; ++k) {
        float4 b = *(const float4*)&W[k * NFF + j0];
        #pragma unroll
        for (int i = 0; i < 4; ++i) {
            float a = xs[i0 + i][k];
            acc[i][0] = fmaf(a, b.x, acc[i][0]);
            acc[i][1] = fmaf(a, b.y, acc[i][1]);
            acc[i][2] = fmaf(a, b.z, acc[i][2]);
            acc[i][3] = fmaf(a, b.w, acc[i][3]);
        }
    }
    #pragma unroll
    for (int i = 0; i < 4; ++i) {
        float4 v = {acc[i][0], acc[i][1], acc[i][2], acc[i][3]};
        *(float4*)&h[(size_t)(n0 + i0 + i) * NFF + j0] = v;
    }
}

// ---- K2: MFMA fused filter-net + gather + modulate + scatter-add ----
// block = 256 thr (4 waves), 64 edges; wave w owns cols [w*64, w*64+64)
__global__ __launch_bounds__(256) void k2_mfma(
        const float* __restrict__ ea, const int* __restrict__ eidx,
        const short* __restrict__ pWf1, const float* __restrict__ bf1v,
        const short* __restrict__ pWf2, const float* __restrict__ bf2v,
        const float* __restrict__ h, float* __restrict__ agg) {
    __shared__ char eaS[64 * 128];   // [64][64] bf16, stride 128B, XOR-swizzled
    __shared__ char t1S[64 * 512];   // [64][256] bf16, stride 512B, XOR-swizzled
    __shared__ int rowS[64], colS[64];
    int e0 = blockIdx.x * 64;
    int tid = threadIdx.x;
    int lane = tid & 63, w = tid >> 6;
    int q = lane >> 4, l15 = lane & 15;

    if (tid < 64) rowS[tid] = eidx[e0 + tid];
    else if (tid < 128) colS[tid - 64] = eidx[NE + e0 + (tid - 64)];

    {   // stage ea -> bf16 swizzled LDS: thread t: row=t>>2, 16 cols at (t&3)*16
        int r = tid >> 2, cp = tid & 3;
        const float4* src = (const float4*)(ea + (size_t)(e0 + r) * ECH + cp * 16);
        float4 f0 = src[0], f1 = src[1], f2 = src[2], f3 = src[3];
        bf16x8 c0 = {bf16r(f0.x), bf16r(f0.y), bf16r(f0.z), bf16r(f0.w),
                     bf16r(f1.x), bf16r(f1.y), bf16r(f1.z), bf16r(f1.w)};
        bf16x8 c1 = {bf16r(f2.x), bf16r(f2.y), bf16r(f2.z), bf16r(f2.w),
                     bf16r(f3.x), bf16r(f3.y), bf16r(f3.z), bf16r(f3.w)};
        int sw = (r & 7) << 4;
        *(bf16x8*)(eaS + r * 128 + ((cp * 32) ^ sw)) = c0;
        *(bf16x8*)(eaS + r * 128 + ((cp * 32 + 16) ^ sw)) = c1;
    }
    __syncthreads();

    f32x4 acc[4][4];
    #pragma unroll
    for (int mf = 0; mf < 4; ++mf)
        #pragma unroll
        for (int nf = 0; nf < 4; ++nf) acc[mf][nf] = f32x4{0.f, 0.f, 0.f, 0.f};

    // phase 1: t1 = ssp(ea @ Wf1 + b1), K=64
    #pragma unroll
    for (int ks = 0; ks < 2; ++ks) {
        bf16x8 a[4];
        #pragma unroll
        for (int mf = 0; mf < 4; ++mf) {
            int row = mf * 16 + l15;
            a[mf] = *(const bf16x8*)(eaS + row * 128 + ((ks * 64 + q * 16) ^ ((row & 7) << 4)));
        }
        #pragma unroll
        for (int nf = 0; nf < 4; ++nf) {
            bf16x8 b = *(const bf16x8*)(pWf1 + (((ks * 16 + w * 4 + nf) * 64) + lane) * 8);
            #pragma unroll
            for (int mf = 0; mf < 4; ++mf)
                acc[mf][nf] = __builtin_amdgcn_mfma_f32_16x16x32_bf16(a[mf], b, acc[mf][nf], 0, 0, 0);
        }
    }
    // ssp + bias, write t1 (bf16, swizzled). C/D layout: col=lane&15, row=(lane>>4)*4+r
    #pragma unroll
    for (int nf = 0; nf < 4; ++nf) {
        int col = w * 64 + nf * 16 + l15;
        float bias = bf1v[col];
        #pragma unroll
        for (int mf = 0; mf < 4; ++mf) {
            #pragma unroll
            for (int r = 0; r < 4; ++r) {
                int row = mf * 16 + q * 4 + r;
                *(short*)(t1S + row * 512 + ((col * 2) ^ ((row & 7) << 4))) =
                    bf16r(sspf(acc[mf][nf][r] + bias));
            }
        }
    }
    __syncthreads();

    #pragma unroll
    for (int mf = 0; mf < 4; ++mf)
        #pragma unroll
        for (int nf = 0; nf < 4; ++nf) acc[mf][nf] = f32x4{0.f, 0.f, 0.f, 0.f};

    // phase 2: Wf = t1 @ Wf2 + b2, K=256
    for (int ks = 0; ks < 8; ++ks) {
        bf16x8 a[4];
        #pragma unroll
        for (int mf = 0; mf < 4; ++mf) {
            int row = mf * 16 + l15;
            a[mf] = *(const bf16x8*)(t1S + row * 512 + ((ks * 64 + q * 16) ^ ((row & 7) << 4)));
        }
        #pragma unroll
        for (int nf = 0; nf < 4; ++nf) {
            bf16x8 b = *(const bf16x8*)(pWf2 + (((ks * 16 + w * 4 + nf) * 64) + lane) * 8);
            #pragma unroll
            for (int mf = 0; mf < 4; ++mf)
                acc[mf][nf] = __builtin_amdgcn_mfma_f32_16x16x32_bf16(a[mf], b, acc[mf][nf], 0, 0, 0);
        }
    }

    // epilogue: gather h[col], modulate, scatter-add agg[row]
    #pragma unroll
    for (int nf = 0; nf < 4; ++nf) {
        int col = w * 64 + nf * 16 + l15;
        float bias = bf2v[col];
        #pragma unroll
        for (int mf = 0; mf < 4; ++mf) {
            #pragma unroll
            for (int r = 0; r < 4; ++r) {
                int eloc = mf * 16 + q * 4 + r;
                float wf = acc[mf][nf][r] + bias;
                float hv = h[(size_t)colS[eloc] * NFF + col];
                atomicAdd(&agg[(size_t)rowS[eloc] * NFF + col], hv * wf);
            }
        }
    }
}

// ---- K3: x_out = relu(ssp(agg@Wl2+b2)@Wl3+b3) + x  (fp32 VALU, small) ----
__global__ __launch_bounds__(128) void k3_node(
        const float* __restrict__ agg,
        const float* __restrict__ Wl2, const float* __restrict__ bl2,
        const float* __restrict__ Wl3, const float* __restrict__ bl3,
        const float* __restrict__ x, float* __restrict__ xo) {
    __shared__ __align__(16) float as[16][NFF];
    __shared__ __align__(16) float t2[16][CC];
    int n0 = blockIdx.x * 16;
    int tid = threadIdx.x;
    for (int i = tid; i < 16 * NFF / 4; i += 128) {
        int nd = i >> 6;
        int c4 = i & 63;
        *(float4*)&as[nd][c4 * 4] = ((const float4*)agg)[(size_t)(n0 + nd) * 64 + c4];
    }
    __syncthreads();
    int j0 = (tid & 31) * 4;
    int i0 = (tid >> 5) * 4;

    float acc[4][4] = {};
    #pragma unroll 4
    for (int k = 0; k < NFF; ++k) {
        float4 b = *(const float4*)&Wl2[k * CC + j0];
        #pragma unroll
        for (int i = 0; i < 4; ++i) {
            float a = as[i0 + i][k];
            acc[i][0] = fmaf(a, b.x, acc[i][0]);
            acc[i][1] = fmaf(a, b.y, acc[i][1]);
            acc[i][2] = fmaf(a, b.z, acc[i][2]);
            acc[i][3] = fmaf(a, b.w, acc[i][3]);
        }
    }
    float4 b2v = *(const float4*)&bl2[j0];
    #pragma unroll
    for (int i = 0; i < 4; ++i) {
        float4 v;
        v.x = sspf(acc[i][0] + b2v.x);
        v.y = sspf(acc[i][1] + b2v.y);
        v.z = sspf(acc[i][2] + b2v.z);
        v.w = sspf(acc[i][3] + b2v.w);
        *(float4*)&t2[i0 + i][j0] = v;
    }
    __syncthreads();

    float acc3[4][4] = {};
    #pragma unroll 4
    for (int k = 0; k < CC; ++k) {
        float4 b = *(const float4*)&Wl3[k * CC + j0];
        #pragma unroll
        for (int i = 0; i < 4; ++i) {
            float a = t2[i0 + i][k];
            acc3[i][0] = fmaf(a, b.x, acc3[i][0]);
            acc3[i][1] = fmaf(a, b.y, acc3[i][1]);
            acc3[i][2] = fmaf(a, b.z, acc3[i][2]);
            acc3[i][3] = fmaf(a, b.w, acc3[i][3]);
        }
    }
    float4 b3v = *(const float4*)&bl3[j0];
    #pragma unroll
    for (int i = 0; i < 4; ++i) {
        size_t base = (size_t)(n0 + i0 + i) * CC + j0;
        float4 xv = *(const float4*)&x[base];
        float4 v;
        v.x = fmaxf(acc3[i][0] + b3v.x, 0.f) + xv.x;
        v.y = fmaxf(acc3[i][1] + b3v.y, 0.f) + xv.y;
        v.z = fmaxf(acc3[i][2] + b3v.z, 0.f) + xv.z;
        v.w = fmaxf(acc3[i][3] + b3v.w, 0.f) + xv.w;
        *(float4*)&xo[base] = v;
    }
}

// ---- K4: MFMA e_out = tanh([ea | xo[row]+xo[col]] @ We + be), K=192, N=128 ----
// block = 256 thr (4 waves), 64 edges; wave w owns edges [w*16, w*16+16), all 128 cols
__global__ __launch_bounds__(256) void k4_mfma(
        const float* __restrict__ ea, const int* __restrict__ eidx,
        const float* __restrict__ xo, const short* __restrict__ pWe,
        const float* __restrict__ bev, float* __restrict__ eo) {
    __shared__ char aS[64 * 384];    // [64][192] bf16, stride 384B, XOR-swizzled
    int e0 = blockIdx.x * 64;
    int tid = threadIdx.x;
    int lane = tid & 63, w = tid >> 6;
    int q = lane >> 4, l15 = lane & 15;

    {   // stage ea (k 0..63)
        int r = tid >> 2, cp = tid & 3;
        const float4* src = (const float4*)(ea + (size_t)(e0 + r) * ECH + cp * 16);
        float4 f0 = src[0], f1 = src[1], f2 = src[2], f3 = src[3];
        bf16x8 c0 = {bf16r(f0.x), bf16r(f0.y), bf16r(f0.z), bf16r(f0.w),
                     bf16r(f1.x), bf16r(f1.y), bf16r(f1.z), bf16r(f1.w)};
        bf16x8 c1 = {bf16r(f2.x), bf16r(f2.y), bf16r(f2.z), bf16r(f2.w),
                     bf16r(f3.x), bf16r(f3.y), bf16r(f3.z), bf16r(f3.w)};
        int sw = (r & 7) << 4;
        *(bf16x8*)(aS + r * 384 + ((cp * 32) ^ sw)) = c0;
        *(bf16x8*)(aS + r * 384 + ((cp * 32 + 16) ^ sw)) = c1;
    }
    {   // stage xo[row]+xo[col] (k 64..191): 4 threads per edge, stride-4 float4s
        int e = tid >> 2, p = tid & 3;
        int rr = eidx[e0 + e], cc = eidx[NE + e0 + e];
        const float4* xr = (const float4*)(xo + (size_t)rr * CC);
        const float4* xc = (const float4*)(xo + (size_t)cc * CC);
        int sw = (e & 7) << 4;
        #pragma unroll
        for (int it = 0; it < 8; ++it) {
            int fi = p + it * 4;          // float4 index 0..31
            float4 va = xr[fi], vb = xc[fi];
            bf16x4 hv = {bf16r(va.x + vb.x), bf16r(va.y + vb.y),
                         bf16r(va.z + vb.z), bf16r(va.w + vb.w)};
            int byte = (ECH + fi * 4) * 2;   // 128 + fi*8
            *(bf16x4*)(aS + e * 384 + (byte ^ sw)) = hv;
        }
    }
    __syncthreads();

    f32x4 acc[8];
    #pragma unroll
    for (int nf = 0; nf < 8; ++nf) acc[nf] = f32x4{0.f, 0.f, 0.f, 0.f};

    #pragma unroll
    for (int ks = 0; ks < 6; ++ks) {
        int row = w * 16 + l15;
        bf16x8 a = *(const bf16x8*)(aS + row * 384 + ((ks * 64 + q * 16) ^ ((row & 7) << 4)));
        #pragma unroll
        for (int nf = 0; nf < 8; ++nf) {
            bf16x8 b = *(const bf16x8*)(pWe + (((ks * 8 + nf) * 64) + lane) * 8);
            acc[nf] = __builtin_amdgcn_mfma_f32_16x16x32_bf16(a, b, acc[nf], 0, 0, 0);
        }
    }
    #pragma unroll
    for (int nf = 0; nf < 8; ++nf) {
        int col = nf * 16 + l15;
        float bias = bev[col];
        #pragma unroll
        for (int r = 0; r < 4; ++r) {
            int e = e0 + w * 16 + q * 4 + r;
            eo[(size_t)e * CC + col] = tanhf(acc[nf][r] + bias);
        }
    }
}

extern "C" void kernel_launch(void* const* d_in, const int* in_sizes, int n_in,
                              void* d_out, int out_size, void* d_ws, size_t ws_size,
                              hipStream_t stream) {
    const float* x   = (const float*)d_in[0];
    const int*   ei  = (const int*)d_in[1];
    const float* ea  = (const float*)d_in[2];
    // d_in[3] = x_pos (unused)
    const float* Wf1 = (const float*)d_in[4];
    const float* bf1 = (const float*)d_in[5];
    const float* Wf2 = (const float*)d_in[6];
    const float* bf2 = (const float*)d_in[7];
    const float* Wl1 = (const float*)d_in[8];
    const float* Wl2 = (const float*)d_in[9];
    const float* bl2 = (const float*)d_in[10];
    const float* Wl3 = (const float*)d_in[11];
    const float* bl3 = (const float*)d_in[12];
    const float* We  = (const float*)d_in[13];
    const float* be  = (const float*)d_in[14];

    float* xo = (float*)d_out;                 // [N, C]
    float* eo = xo + (size_t)NN * CC;          // [E, C]

    // ws layout: [packed weights 256KB][agg 51.2MB][h 51.2MB if it fits]
    short* pW  = (short*)d_ws;
    short* pWf1 = pW;
    short* pWf2 = pW + 16384;
    short* pWe  = pW + 81920;
    float* agg = (float*)((char*)d_ws + 262144);
    size_t one = (size_t)NN * NFF;
    float* h = (ws_size >= 262144 + 2 * one * sizeof(float)) ? (agg + one) : eo;

    kpack<<<416, 256, 0, stream>>>(Wf1, Wf2, We, pW);
    k0_zero<<<1024, 256, 0, stream>>>(agg, (long)(one / 4));
    k1_h<<<NN / 16, 256, 0, stream>>>(x, Wl1, h);
    k2_mfma<<<NE / 64, 256, 0, stream>>>(ea, ei, pWf1, bf1, pWf2, bf2, h, agg);
    k3_node<<<NN / 16, 128, 0, stream>>>(agg, Wl2, bl2, Wl3, bl3, x, xo);
    k4_mfma<<<NE / 64, 256, 0, stream>>>(ea, ei, xo, pWe, be, eo);
}

// Round 3
// 1374.096 us; speedup vs baseline: 2.1821x; 1.2850x over previous
//
#include <hip/hip_runtime.h>

#define NN  50000
#define NE  600000
#define CC  128
#define NFF 256
#define ECH 64
#define EIN 192   // ECH + CC

typedef __attribute__((ext_vector_type(8))) short bf16x8;
typedef __attribute__((ext_vector_type(4))) short bf16x4;
typedef __attribute__((ext_vector_type(4))) float f32x4;

__device__ __forceinline__ float sspf(float v) {
    float sp = (v > 0.0f) ? (v + log1pf(__expf(-v))) : log1pf(__expf(v));
    return sp - 0.693147180559945f;
}
// fp32 -> bf16 round-to-nearest-even
__device__ __forceinline__ short bf16r(float f) {
    unsigned u = __float_as_uint(f);
    u = (u + 0x7FFFu + ((u >> 16) & 1u)) >> 16;
    return (short)u;
}
__device__ __forceinline__ float bf2f(short s) {
    unsigned u = ((unsigned)(unsigned short)s) << 16;
    return __uint_as_float(u);
}

// ---- pack weights to bf16 fragment-linear layout for mfma_16x16x32 B-operand
// packed[((ks*(N/16)+n16)*64 + lane)*8 + j] = B[ks*32 + (lane>>4)*8 + j][n16*16 + (lane&15)]
__global__ void kpack(const float* __restrict__ Wf1, const float* __restrict__ Wf2,
                      const float* __restrict__ We, short* __restrict__ p) {
    int i = blockIdx.x * 256 + threadIdx.x;
    if (i < 16384) {                       // Wf1 [64][256]: ks 0..1, n16 0..15
        int j = i & 7, lane = (i >> 3) & 63, n16 = (i >> 9) & 15, ks = i >> 13;
        int k = ks * 32 + (lane >> 4) * 8 + j, col = n16 * 16 + (lane & 15);
        p[i] = bf16r(Wf1[k * NFF + col]);
    } else if (i < 16384 + 65536) {        // Wf2 [256][256]: ks 0..7
        int t = i - 16384;
        int j = t & 7, lane = (t >> 3) & 63, n16 = (t >> 9) & 15, ks = t >> 13;
        int k = ks * 32 + (lane >> 4) * 8 + j, col = n16 * 16 + (lane & 15);
        p[i] = bf16r(Wf2[k * NFF + col]);
    } else if (i < 16384 + 65536 + 24576) { // We [192][128]: ks 0..5, n16 0..7
        int t = i - 81920;
        int j = t & 7, lane = (t >> 3) & 63, n16 = (t >> 9) & 7, ks = t >> 12;
        int k = ks * 32 + (lane >> 4) * 8 + j, col = n16 * 16 + (lane & 15);
        p[i] = bf16r(We[k * CC + col]);
    }
}

// ---- K0: zero agg ----
__global__ void k0_zero(float* __restrict__ p, long n4) {
    long i = (long)blockIdx.x * blockDim.x + threadIdx.x;
    long stride = (long)gridDim.x * blockDim.x;
    float4 z = {0.f, 0.f, 0.f, 0.f};
    for (; i < n4; i += stride) ((float4*)p)[i] = z;
}

// ---- K1: h[N,NF] = x[N,C] @ W_lin1[C,NF], output bf16 ----
__global__ __launch_bounds__(256) void k1_h(const float* __restrict__ x,
                                            const float* __restrict__ W,
                                            short* __restrict__ h) {
    __shared__ __align__(16) float xs[16][CC];
    int n0 = blockIdx.x * 16;
    int tid = threadIdx.x;
    for (int i = tid; i < 16 * CC / 4; i += 256) {
        int nd = i >> 5;
        int c4 = i & 31;
        *(float4*)&xs[nd][c4 * 4] = ((const float4*)x)[(size_t)(n0 + nd) * 32 + c4];
    }
    __syncthreads();
    int j0 = (tid & 63) * 4;
    int i0 = (tid >> 6) * 4;
    float acc[4][4] = {};
    #pragma unroll 4
    for (int k = 0; k < CC; ++k) {
        float4 b = *(const float4*)&W[k * NFF + j0];
        #pragma unroll
        for (int i = 0; i < 4; ++i) {
            float a = xs[i0 + i][k];
            acc[i][0] = fmaf(a, b.x, acc[i][0]);
            acc[i][1] = fmaf(a, b.y, acc[i][1]);
            acc[i][2] = fmaf(a, b.z, acc[i][2]);
            acc[i][3] = fmaf(a, b.w, acc[i][3]);
        }
    }
    #pragma unroll
    for (int i = 0; i < 4; ++i) {
        bf16x4 v = {bf16r(acc[i][0]), bf16r(acc[i][1]), bf16r(acc[i][2]), bf16r(acc[i][3])};
        *(bf16x4*)&h[(size_t)(n0 + i0 + i) * NFF + j0] = v;
    }
}

// ---- K2: MFMA fused filter-net + gather + modulate + scatter-add ----
// block = 256 thr (4 waves), 32 edges; wave w owns cols [w*64, w*64+64)
__global__ __launch_bounds__(256, 6) void k2_mfma(
        const float* __restrict__ ea, const int* __restrict__ eidx,
        const short* __restrict__ pWf1, const float* __restrict__ bf1v,
        const short* __restrict__ pWf2, const float* __restrict__ bf2v,
        const short* __restrict__ h, float* __restrict__ agg) {
    __shared__ char eaS[32 * 128];   // [32][64] bf16, stride 128B, XOR-swizzled
    __shared__ char t1S[32 * 512];   // [32][256] bf16, stride 512B, XOR-swizzled
    __shared__ int rowS[32], colS[32];
    int e0 = blockIdx.x * 32;
    int tid = threadIdx.x;
    int lane = tid & 63, w = tid >> 6;
    int q = lane >> 4, l15 = lane & 15;

    if (tid < 32) rowS[tid] = eidx[e0 + tid];
    else if (tid < 64) colS[tid - 32] = eidx[NE + e0 + (tid - 32)];

    {   // stage ea -> bf16 swizzled LDS: thread t: row=t>>3, 8 cols at (t&7)*8
        int r = tid >> 3, cp = tid & 7;
        const float4* src = (const float4*)(ea + (size_t)(e0 + r) * ECH + cp * 8);
        float4 f0 = src[0], f1 = src[1];
        bf16x8 c0 = {bf16r(f0.x), bf16r(f0.y), bf16r(f0.z), bf16r(f0.w),
                     bf16r(f1.x), bf16r(f1.y), bf16r(f1.z), bf16r(f1.w)};
        int sw = (r & 7) << 4;
        *(bf16x8*)(eaS + r * 128 + ((cp * 16) ^ sw)) = c0;
    }
    __syncthreads();

    f32x4 acc[2][4];
    #pragma unroll
    for (int mf = 0; mf < 2; ++mf)
        #pragma unroll
        for (int nf = 0; nf < 4; ++nf) acc[mf][nf] = f32x4{0.f, 0.f, 0.f, 0.f};

    // phase 1: t1 = ssp(ea @ Wf1 + b1), K=64, M=32
    #pragma unroll
    for (int ks = 0; ks < 2; ++ks) {
        bf16x8 a[2];
        #pragma unroll
        for (int mf = 0; mf < 2; ++mf) {
            int row = mf * 16 + l15;
            a[mf] = *(const bf16x8*)(eaS + row * 128 + ((ks * 64 + q * 16) ^ ((row & 7) << 4)));
        }
        #pragma unroll
        for (int nf = 0; nf < 4; ++nf) {
            bf16x8 b = *(const bf16x8*)(pWf1 + (((ks * 16 + w * 4 + nf) * 64) + lane) * 8);
            #pragma unroll
            for (int mf = 0; mf < 2; ++mf)
                acc[mf][nf] = __builtin_amdgcn_mfma_f32_16x16x32_bf16(a[mf], b, acc[mf][nf], 0, 0, 0);
        }
    }
    // ssp + bias, write t1 (bf16, swizzled). C/D: col=lane&15, row=(lane>>4)*4+r
    #pragma unroll
    for (int nf = 0; nf < 4; ++nf) {
        int col = w * 64 + nf * 16 + l15;
        float bias = bf1v[col];
        #pragma unroll
        for (int mf = 0; mf < 2; ++mf) {
            #pragma unroll
            for (int r = 0; r < 4; ++r) {
                int row = mf * 16 + q * 4 + r;
                *(short*)(t1S + row * 512 + ((col * 2) ^ ((row & 7) << 4))) =
                    bf16r(sspf(acc[mf][nf][r] + bias));
            }
        }
    }
    __syncthreads();

    #pragma unroll
    for (int mf = 0; mf < 2; ++mf)
        #pragma unroll
        for (int nf = 0; nf < 4; ++nf) acc[mf][nf] = f32x4{0.f, 0.f, 0.f, 0.f};

    // phase 2: Wf = t1 @ Wf2 + b2, K=256, M=32
    for (int ks = 0; ks < 8; ++ks) {
        bf16x8 a[2];
        #pragma unroll
        for (int mf = 0; mf < 2; ++mf) {
            int row = mf * 16 + l15;
            a[mf] = *(const bf16x8*)(t1S + row * 512 + ((ks * 64 + q * 16) ^ ((row & 7) << 4)));
        }
        #pragma unroll
        for (int nf = 0; nf < 4; ++nf) {
            bf16x8 b = *(const bf16x8*)(pWf2 + (((ks * 16 + w * 4 + nf) * 64) + lane) * 8);
            #pragma unroll
            for (int mf = 0; mf < 2; ++mf)
                acc[mf][nf] = __builtin_amdgcn_mfma_f32_16x16x32_bf16(a[mf], b, acc[mf][nf], 0, 0, 0);
        }
    }

    // epilogue: gather h[col] (bf16), modulate, scatter-add agg[row]
    #pragma unroll
    for (int nf = 0; nf < 4; ++nf) {
        int col = w * 64 + nf * 16 + l15;
        float bias = bf2v[col];
        #pragma unroll
        for (int mf = 0; mf < 2; ++mf) {
            #pragma unroll
            for (int r = 0; r < 4; ++r) {
                int eloc = mf * 16 + q * 4 + r;
                float wf = acc[mf][nf][r] + bias;
                float hv = bf2f(h[(size_t)colS[eloc] * NFF + col]);
                atomicAdd(&agg[(size_t)rowS[eloc] * NFF + col], hv * wf);
            }
        }
    }
}

// ---- K3: x_out = relu(ssp(agg@Wl2+b2)@Wl3+b3) + x ----
__global__ __launch_bounds__(128) void k3_node(
        const float* __restrict__ agg,
        const float* __restrict__ Wl2, const float* __restrict__ bl2,
        const float* __restrict__ Wl3, const float* __restrict__ bl3,
        const float* __restrict__ x, float* __restrict__ xo) {
    __shared__ __align__(16) float as[16][NFF];
    __shared__ __align__(16) float t2[16][CC];
    int n0 = blockIdx.x * 16;
    int tid = threadIdx.x;
    for (int i = tid; i < 16 * NFF / 4; i += 128) {
        int nd = i >> 6;
        int c4 = i & 63;
        *(float4*)&as[nd][c4 * 4] = ((const float4*)agg)[(size_t)(n0 + nd) * 64 + c4];
    }
    __syncthreads();
    int j0 = (tid & 31) * 4;
    int i0 = (tid >> 5) * 4;

    float acc[4][4] = {};
    #pragma unroll 4
    for (int k = 0; k < NFF; ++k) {
        float4 b = *(const float4*)&Wl2[k * CC + j0];
        #pragma unroll
        for (int i = 0; i < 4; ++i) {
            float a = as[i0 + i][k];
            acc[i][0] = fmaf(a, b.x, acc[i][0]);
            acc[i][1] = fmaf(a, b.y, acc[i][1]);
            acc[i][2] = fmaf(a, b.z, acc[i][2]);
            acc[i][3] = fmaf(a, b.w, acc[i][3]);
        }
    }
    float4 b2v = *(const float4*)&bl2[j0];
    #pragma unroll
    for (int i = 0; i < 4; ++i) {
        float4 v;
        v.x = sspf(acc[i][0] + b2v.x);
        v.y = sspf(acc[i][1] + b2v.y);
        v.z = sspf(acc[i][2] + b2v.z);
        v.w = sspf(acc[i][3] + b2v.w);
        *(float4*)&t2[i0 + i][j0] = v;
    }
    __syncthreads();

    float acc3[4][4] = {};
    #pragma unroll 4
    for (int k = 0; k < CC; ++k) {
        float4 b = *(const float4*)&Wl3[k * CC + j0];
        #pragma unroll
        for (int i = 0; i < 4; ++i) {
            float a = t2[i0 + i][k];
            acc3[i][0] = fmaf(a, b.x, acc3[i][0]);
            acc3[i][1] = fmaf(a, b.y, acc3[i][1]);
            acc3[i][2] = fmaf(a, b.z, acc3[i][2]);
            acc3[i][3] = fmaf(a, b.w, acc3[i][3]);
        }
    }
    float4 b3v = *(const float4*)&bl3[j0];
    #pragma unroll
    for (int i = 0; i < 4; ++i) {
        size_t base = (size_t)(n0 + i0 + i) * CC + j0;
        float4 xv = *(const float4*)&x[base];
        float4 v;
        v.x = fmaxf(acc3[i][0] + b3v.x, 0.f) + xv.x;
        v.y = fmaxf(acc3[i][1] + b3v.y, 0.f) + xv.y;
        v.z = fmaxf(acc3[i][2] + b3v.z, 0.f) + xv.z;
        v.w = fmaxf(acc3[i][3] + b3v.w, 0.f) + xv.w;
        *(float4*)&xo[base] = v;
    }
}

// ---- K4: MFMA e_out = tanh([ea | xo[row]+xo[col]] @ We + be), K=192, N=128 ----
__global__ __launch_bounds__(256) void k4_mfma(
        const float* __restrict__ ea, const int* __restrict__ eidx,
        const float* __restrict__ xo, const short* __restrict__ pWe,
        const float* __restrict__ bev, float* __restrict__ eo) {
    __shared__ char aS[64 * 384];    // [64][192] bf16, stride 384B, XOR-swizzled
    int e0 = blockIdx.x * 64;
    int tid = threadIdx.x;
    int lane = tid & 63, w = tid >> 6;
    int q = lane >> 4, l15 = lane & 15;

    {   // stage ea (k 0..63)
        int r = tid >> 2, cp = tid & 3;
        const float4* src = (const float4*)(ea + (size_t)(e0 + r) * ECH + cp * 16);
        float4 f0 = src[0], f1 = src[1], f2 = src[2], f3 = src[3];
        bf16x8 c0 = {bf16r(f0.x), bf16r(f0.y), bf16r(f0.z), bf16r(f0.w),
                     bf16r(f1.x), bf16r(f1.y), bf16r(f1.z), bf16r(f1.w)};
        bf16x8 c1 = {bf16r(f2.x), bf16r(f2.y), bf16r(f2.z), bf16r(f2.w),
                     bf16r(f3.x), bf16r(f3.y), bf16r(f3.z), bf16r(f3.w)};
        int sw = (r & 7) << 4;
        *(bf16x8*)(aS + r * 384 + ((cp * 32) ^ sw)) = c0;
        *(bf16x8*)(aS + r * 384 + ((cp * 32 + 16) ^ sw)) = c1;
    }
    {   // stage xo[row]+xo[col] (k 64..191)
        int e = tid >> 2, p = tid & 3;
        int rr = eidx[e0 + e], cc = eidx[NE + e0 + e];
        const float4* xr = (const float4*)(xo + (size_t)rr * CC);
        const float4* xc = (const float4*)(xo + (size_t)cc * CC);
        int sw = (e & 7) << 4;
        #pragma unroll
        for (int it = 0; it < 8; ++it) {
            int fi = p + it * 4;
            float4 va = xr[fi], vb = xc[fi];
            bf16x4 hv = {bf16r(va.x + vb.x), bf16r(va.y + vb.y),
                         bf16r(va.z + vb.z), bf16r(va.w + vb.w)};
            int byte = (ECH + fi * 4) * 2;
            *(bf16x4*)(aS + e * 384 + (byte ^ sw)) = hv;
        }
    }
    __syncthreads();

    f32x4 acc[8];
    #pragma unroll
    for (int nf = 0; nf < 8; ++nf) acc[nf] = f32x4{0.f, 0.f, 0.f, 0.f};

    #pragma unroll
    for (int ks = 0; ks < 6; ++ks) {
        int row = w * 16 + l15;
        bf16x8 a = *(const bf16x8*)(aS + row * 384 + ((ks * 64 + q * 16) ^ ((row & 7) << 4)));
        #pragma unroll
        for (int nf = 0; nf < 8; ++nf) {
            bf16x8 b = *(const bf16x8*)(pWe + (((ks * 8 + nf) * 64) + lane) * 8);
            acc[nf] = __builtin_amdgcn_mfma_f32_16x16x32_bf16(a, b, acc[nf], 0, 0, 0);
        }
    }
    #pragma unroll
    for (int nf = 0; nf < 8; ++nf) {
        int col = nf * 16 + l15;
        float bias = bev[col];
        #pragma unroll
        for (int r = 0; r < 4; ++r) {
            int e = e0 + w * 16 + q * 4 + r;
            eo[(size_t)e * CC + col] = tanhf(acc[nf][r] + bias);
        }
    }
}

extern "C" void kernel_launch(void* const* d_in, const int* in_sizes, int n_in,
                              void* d_out, int out_size, void* d_ws, size_t ws_size,
                              hipStream_t stream) {
    const float* x   = (const float*)d_in[0];
    const int*   ei  = (const int*)d_in[1];
    const float* ea  = (const float*)d_in[2];
    const float* Wf1 = (const float*)d_in[4];
    const float* bf1 = (const float*)d_in[5];
    const float* Wf2 = (const float*)d_in[6];
    const float* bf2 = (const float*)d_in[7];
    const float* Wl1 = (const float*)d_in[8];
    const float* Wl2 = (const float*)d_in[9];
    const float* bl2 = (const float*)d_in[10];
    const float* Wl3 = (const float*)d_in[11];
    const float* bl3 = (const float*)d_in[12];
    const float* We  = (const float*)d_in[13];
    const float* be  = (const float*)d_in[14];

    float* xo = (float*)d_out;                 // [N, C]
    float* eo = xo + (size_t)NN * CC;          // [E, C]

    // ws layout: [packed weights 256KB][agg 51.2MB][h bf16 25.6MB if it fits]
    short* pW   = (short*)d_ws;
    short* pWf1 = pW;
    short* pWf2 = pW + 16384;
    short* pWe  = pW + 81920;
    float* agg = (float*)((char*)d_ws + 262144);
    size_t one = (size_t)NN * NFF;
    size_t need_h = 262144 + one * sizeof(float) + one * sizeof(short);
    short* h = (ws_size >= need_h) ? (short*)(agg + one) : (short*)eo;

    kpack<<<416, 256, 0, stream>>>(Wf1, Wf2, We, pW);
    k0_zero<<<1024, 256, 0, stream>>>(agg, (long)(one / 4));
    k1_h<<<NN / 16, 256, 0, stream>>>(x, Wl1, h);
    k2_mfma<<<NE / 32, 256, 0, stream>>>(ea, ei, pWf1, bf1, pWf2, bf2, h, agg);
    k3_node<<<NN / 16, 128, 0, stream>>>(agg, Wl2, bl2, Wl3, bl3, x, xo);
    k4_mfma<<<NE / 64, 256, 0, stream>>>(ea, ei, xo, pWe, be, eo);
}